// Round 1
// baseline (248.232 us; speedup 1.0000x reference)
//
#include <hip/hip_runtime.h>
#include <cstdint>
#include <cstddef>

// ---------------------------------------------------------------------------
// SparseMHADecoder: B=2, LQ=4096, LKV=2048, D=1024, H=16, d=64, span=16, stride=2
// R7: replace the m97-style 2-barrier gemm_body with a distance-2 software-
//     pipelined GEMM (T3/T4-class): 256-row tile, BK=64, 8 waves, double-
//     buffered LDS, reg-staged A+B (compiler-counted vmcnt only), ONE raw
//     s_barrier per K-tile, global prefetch in flight across the barrier,
//     setprio around MFMA clusters (T5). qkv: 256x256 (2x4 waves), 256 blocks
//     = 1/CU, XCD-grouped; out: 256x128 (4x2 waves), 256 blocks.
// R6 carried: f32->f16 A-convert folded into gemm_qkv staging.
// R5 carried: XOR chunk swizzle (verified conflict-free for reads AND the new
//     ds_write staging), fp16 numerics (identical accumulation order).
// ---------------------------------------------------------------------------

typedef _Float16 f16;
typedef _Float16 f16x8 __attribute__((ext_vector_type(8)));
typedef float v4f __attribute__((ext_vector_type(4)));

#define B_  2
#define LQ_ 4096
#define LKV_ 2048
#define DMODEL 1024
#define NH 16
#define HD 64
#define SPAN 16
#define STRIDE 2

#define NQ_ELEMS  ((size_t)B_ * LQ_ * DMODEL)   // 8388608
#define NKV_ELEMS ((size_t)B_ * LKV_ * DMODEL)  // 4194304

// ------------- prep: 4 weight transposes, Wt[n][k] = (f16)W[k][n] ------------
__global__ __launch_bounds__(256)
void transpose_all(const float* __restrict__ W0, const float* __restrict__ W1,
                   const float* __restrict__ W2, const float* __restrict__ W3,
                   f16* __restrict__ T0, f16* __restrict__ T1,
                   f16* __restrict__ T2, f16* __restrict__ T3) {
    const int t = threadIdx.x;
    const int bid = blockIdx.x;             // 1024 = 16x16 tiles x 4 weights
    const int z = bid >> 8, rem = bid & 255;
    const int bx = rem & 15, byy = rem >> 4;
    const float* W;
    f16* Wt;
    switch (z) {
        case 0: W = W0; Wt = T0; break;
        case 1: W = W1; Wt = T1; break;
        case 2: W = W2; Wt = T2; break;
        default: W = W3; Wt = T3; break;
    }
    __shared__ float tile[64][65];
    const int r0 = byy * 64, c0 = bx * 64;
    const int tx = t & 63, ty = t >> 6;     // (64,4)
    for (int i = ty; i < 64; i += 4)
        tile[i][tx] = W[(long)(r0 + i) * DMODEL + c0 + tx];
    __syncthreads();
    for (int i = ty; i < 64; i += 4)
        Wt[(long)(c0 + i) * DMODEL + r0 + tx] = (f16)tile[tx][i];
}

// ---------------------------------------------------------------------------
// Pipelined fp16 GEMM: C[m][n] = sum_k A[m][k] * Bt[n][k]
// BM=256 rows, BN cols, BK=64, 512 threads = 8 waves (WM x WN).
// LDS double-buffered; per K-tile: one lgkmcnt(0)+s_barrier.
// Pipeline: iter t computes tile t, ds_writes tile t+1 (regs from iter t-1),
// issues global loads for tile t+2. All global->reg: the compiler emits the
// counted vmcnt before each use, so prefetch stays in flight across barriers.
// Swizzle: LDS chunk c of row r holds global chunk c^(r&7)  (involution).
// ---------------------------------------------------------------------------
template <bool A_F32, bool OUT_F32, int BN, int WM, int WN, int MR, int NR>
__device__ __forceinline__ void gemm_pipe(const void* __restrict__ Av,
                                          const f16* __restrict__ Bt,
                                          void* __restrict__ Cv,
                                          int rowTile, int colTile) {
    constexpr int BM = 256, BK = 64, K = DMODEL, N = DMODEL, NT = K / BK;
    static_assert(WM * MR * 16 == BM, "BM decomposition");
    static_assert(WN * NR * 16 == BN, "BN decomposition");
    constexpr int LA = BM * BK;             // f16 elems per A tile (16384)
    constexpr int LB = BN * BK;
    constexpr int LT = LA + LB;
    __shared__ f16 lds[2 * LT];             // qkv: 128 KB, out: 96 KB

    const int t = threadIdx.x;              // 512
    const int lane = t & 63, w = t >> 6;
    const int wm = w / WN, wn = w % WN;
    const int qrow = lane & 15, quad = lane >> 4;
    const long rowBase = (long)rowTile * BM;
    const long colBase = (long)colTile * BN;

    // ---- staging geometry (A: 2 thr/row covering 32 k-elems each) ----
    const int arow = t >> 1, ah = t & 1;
    constexpr int TPRB = 512 / BN;          // B threads per row (2 or 4)
    constexpr int CPTB = 8 / TPRB;          // B 8-f16 chunks per thread
    const int brow = t / TPRB, bsub = t % TPRB;

    const float* gAf = (const float*)Av + (rowBase + arow) * (long)K + ah * 32;
    const f16*   gAh = (const f16*)Av + (rowBase + arow) * (long)K + ah * 32;
    const f16*   gB  = Bt + (colBase + brow) * (long)K + bsub * (CPTB * 8);

    // LDS element offsets (swizzled; verified conflict-free per 8-lane group)
    int offA[4], offB[CPTB];
#pragma unroll
    for (int j = 0; j < 4; ++j)
        offA[j] = arow * BK + (((ah * 4 + j) ^ (arow & 7)) * 8);
#pragma unroll
    for (int j = 0; j < CPTB; ++j)
        offB[j] = LA + brow * BK + (((bsub * CPTB + j) ^ (brow & 7)) * 8);

    int offAf[MR], offBf[NR];
#pragma unroll
    for (int m = 0; m < MR; ++m) offAf[m] = (wm * (MR * 16) + m * 16 + qrow) * BK;
#pragma unroll
    for (int n = 0; n < NR; ++n) offBf[n] = LA + (wn * (NR * 16) + n * 16 + qrow) * BK;

    // staging register sets (double-buffered; indices become compile-time
    // constants after full unroll -> no scratch, rule #20)
    float4 ra[2][8];
    f16x8  rah[2][4];
    f16x8  rb[2][CPTB];
    v4f acc[MR][NR] = {};

    auto LOAD = [&](int tt, int ss) {
        if constexpr (A_F32) {
#pragma unroll
            for (int j = 0; j < 8; ++j)
                ra[ss][j] = *(const float4*)(gAf + tt * BK + 4 * j);
        } else {
#pragma unroll
            for (int j = 0; j < 4; ++j)
                rah[ss][j] = *(const f16x8*)(gAh + tt * BK + 8 * j);
        }
#pragma unroll
        for (int j = 0; j < CPTB; ++j)
            rb[ss][j] = *(const f16x8*)(gB + tt * BK + 8 * j);
    };

    auto WRITE = [&](int tt, int ss) {
        f16* lp = &lds[(tt & 1) * LT];
        if constexpr (A_F32) {
#pragma unroll
            for (int j = 0; j < 4; ++j) {
                float4 lo = ra[ss][2 * j], hi = ra[ss][2 * j + 1];
                f16x8 o = {(f16)lo.x, (f16)lo.y, (f16)lo.z, (f16)lo.w,
                           (f16)hi.x, (f16)hi.y, (f16)hi.z, (f16)hi.w};
                *(f16x8*)(lp + offA[j]) = o;
            }
        } else {
#pragma unroll
            for (int j = 0; j < 4; ++j)
                *(f16x8*)(lp + offA[j]) = rah[ss][j];
        }
#pragma unroll
        for (int j = 0; j < CPTB; ++j)
            *(f16x8*)(lp + offB[j]) = rb[ss][j];
    };

    auto COMPUTE = [&](int tt) {
        const f16* lp = &lds[(tt & 1) * LT];
#pragma unroll
        for (int s = 0; s < 2; ++s) {
            const int xk = ((s * 4 + quad) ^ (qrow & 7)) * 8;
            f16x8 afr[MR], bfr[NR];
#pragma unroll
            for (int m = 0; m < MR; ++m) afr[m] = *(const f16x8*)(lp + offAf[m] + xk);
#pragma unroll
            for (int n = 0; n < NR; ++n) bfr[n] = *(const f16x8*)(lp + offBf[n] + xk);
            __builtin_amdgcn_s_setprio(1);
#pragma unroll
            for (int m = 0; m < MR; ++m)
#pragma unroll
                for (int n = 0; n < NR; ++n)
                    acc[m][n] = __builtin_amdgcn_mfma_f32_16x16x32_f16(
                        afr[m], bfr[n], acc[m][n], 0, 0, 0);
            __builtin_amdgcn_s_setprio(0);
        }
    };

    // ---- prologue: tile0 staged, tile1 loads in flight ----
    LOAD(0, 0);
    LOAD(1, 1);              // issued early; latency hidden under WRITE+barrier
    WRITE(0, 0);             // compiler waits only tile0's loads (counted)
    asm volatile("s_waitcnt lgkmcnt(0)" ::: "memory");
    __builtin_amdgcn_s_barrier();
    asm volatile("" ::: "memory");

    // ---- main loop: fully unrolled, one barrier per K-tile ----
#pragma unroll
    for (int tt = 0; tt < NT; ++tt) {
        if (tt + 1 < NT) WRITE(tt + 1, (tt + 1) & 1);  // regs from iter tt-1
        if (tt + 2 < NT) LOAD(tt + 2, tt & 1);         // in flight across barrier
        COMPUTE(tt);
        if (tt + 1 < NT) {
            asm volatile("s_waitcnt lgkmcnt(0)" ::: "memory");
            __builtin_amdgcn_s_barrier();
            asm volatile("" ::: "memory");
        }
    }

    // ---- epilogue: C/D layout (m89-verified): row = quad*4 + r, col = qrow --
#pragma unroll
    for (int m = 0; m < MR; ++m)
#pragma unroll
        for (int n = 0; n < NR; ++n) {
            const long col = colBase + wn * (NR * 16) + n * 16 + qrow;
#pragma unroll
            for (int r = 0; r < 4; ++r) {
                const long row = rowBase + wm * (MR * 16) + m * 16 + quad * 4 + r;
                if constexpr (OUT_F32)
                    ((float*)Cv)[row * (long)N + col] = acc[m][n][r];
                else
                    ((f16*)Cv)[row * (long)N + col] = (f16)acc[m][n][r];
            }
        }
}

// Fused Q/K/V projection from ORIGINAL f32 inputs. 256 blocks x 512 thr =
// exactly 1 block/CU, one round. XCD-grouped: blocks with the same (b&7) form
// one 32-block group = one (proj, colTile) B-panel resident in that XCD's L2.
__global__ __launch_bounds__(512, 2)
void gemm_qkv(const float* __restrict__ q, const float* __restrict__ k,
              const float* __restrict__ v, const f16* __restrict__ WqT,
              const f16* __restrict__ WkT, const f16* __restrict__ WvT,
              f16* __restrict__ Qh, f16* __restrict__ Kh, f16* __restrict__ Vh) {
    const int id = (blockIdx.x & 7) * 32 + (blockIdx.x >> 3);  // bijective, 256
    const float* A; const f16* Bt; f16* C; int rt, ct;
    if (id < 128)      { A = q; Bt = WqT; C = Qh; ct = id >> 5; rt = id & 31; }
    else if (id < 192) { const int g = id - 128; A = k; Bt = WkT; C = Kh; ct = g >> 4; rt = g & 15; }
    else               { const int g = id - 192; A = v; Bt = WvT; C = Vh; ct = g >> 4; rt = g & 15; }
    gemm_pipe<true, false, 256, 2, 4, 8, 4>((const void*)A, Bt, (void*)C, rt, ct);
}

// Output projection (f16 in, f32 out). 256x128 tile -> 32x8 = 256 blocks.
__global__ __launch_bounds__(512, 2)
void gemm_out(const f16* __restrict__ A, const f16* __restrict__ Bt,
              float* __restrict__ C) {
    const int id = (blockIdx.x & 7) * 32 + (blockIdx.x >> 3);
    const int ct = id >> 5, rt = id & 31;
    gemm_pipe<false, true, 128, 4, 2, 4, 4>((const void*)A, Bt, (void*)C, rt, ct);
}

// -------- per-column scores + softmax over the 16 valid query rows ----------
__global__ __launch_bounds__(256)
void attn_scores(const f16* __restrict__ Q, const f16* __restrict__ Km,
                 float* __restrict__ attnw) {
    const int c0 = blockIdx.x * 4, b = blockIdx.y;
    const int t = threadIdx.x;
    __shared__ f16 Qs[24 * 1032];   // rows 0..21 used; 49.5 KB
    __shared__ f16 Ks[4 * 1032];    // 8.25 KB

#pragma unroll
    for (int it = 0; it < 12; ++it) {
        const int ch = t + 256 * it;        // 24 rows x 128 chunks
        const int row = ch >> 7, off = (ch & 127) * 8;
        int qq = 2 * c0 + row;
        if (qq > LQ_ - 1) qq = LQ_ - 1;     // clamp staging; masked in score
        f16x8 x = *(const f16x8*)(Q + (size_t)(b * LQ_ + qq) * DMODEL + off);
        const int h = off >> 6, bb = (off >> 3) & 7;
        *(f16x8*)(&Qs[row * 1032 + h * 64 + ((bb + h) & 7) * 8]) = x;
    }
#pragma unroll
    for (int it = 0; it < 2; ++it) {
        const int ch = t + 256 * it;        // 4 rows x 128 chunks
        const int row = ch >> 7, off = (ch & 127) * 8;
        f16x8 x = *(const f16x8*)(Km + (size_t)(b * LKV_ + c0 + row) * DMODEL + off);
        const int h = off >> 6, bb = (off >> 3) & 7;
        *(f16x8*)(&Ks[row * 1032 + h * 64 + ((bb + h) & 7) * 8]) = x;
    }
    __syncthreads();

    const int h = t >> 4, j = t & 15;
#pragma unroll
    for (int ci = 0; ci < 4; ++ci) {
        const int c = c0 + ci;
        const int q = STRIDE * c + j;
        const int row = 2 * ci + j;
        float a = 0.f;
#pragma unroll
        for (int bb = 0; bb < 8; ++bb) {
            const int off = h * 64 + ((bb + h) & 7) * 8;
            f16x8 qv = *(const f16x8*)(&Qs[row * 1032 + off]);
            f16x8 kv = *(const f16x8*)(&Ks[ci * 1032 + off]);  // wave-broadcast
#pragma unroll
            for (int u = 0; u < 8; ++u) a += (float)qv[u] * (float)kv[u];
        }
        float s = (q < LQ_) ? a : -1e30f;
        float m = s;
#pragma unroll
        for (int o = 1; o < 16; o <<= 1) m = fmaxf(m, __shfl_xor(m, o, 64));
        float p = (q < LQ_) ? __expf(s - m) : 0.f;
        float sum = p;
#pragma unroll
        for (int o = 1; o < 16; o <<= 1) sum += __shfl_xor(sum, o, 64);
        attnw[(size_t)((b * LKV_ + c) * NH + h) * SPAN + j] = p / sum;
    }
}

// ---- ctx[b,q,h,:] = sum_i attn[b, q/2-i, h, (q&1)+2i] * V[b, q/2-i, h, :] ----
__global__ __launch_bounds__(256)
void ctx_gather(const float* __restrict__ attnw, const f16* __restrict__ V,
                f16* __restrict__ ctx) {
    const int q0 = blockIdx.x * 16, b = blockIdx.y;
    const int t = threadIdx.x;
    const int kbase = (q0 >> 1) - 7;
    __shared__ f16 Vs[16 * 1024];     // 32 KB
    __shared__ float A_lds[16 * 256]; // 16 KB

#pragma unroll
    for (int it = 0; it < 8; ++it) {
        const int ch = t + 256 * it;       // 16 rows x 128 chunks
        const int row = ch >> 7, off = (ch & 127) * 8;
        int k = kbase + row;
        k = (k < 0) ? 0 : ((k > LKV_ - 1) ? LKV_ - 1 : k);
        *(f16x8*)(&Vs[row * 1024 + off]) =
            *(const f16x8*)(V + (size_t)(b * LKV_ + k) * DMODEL + off);
    }
#pragma unroll
    for (int it = 0; it < 4; ++it) {
        const int ch = t + 256 * it;       // 16 rows x 64 chunks of 4 f32
        const int row = ch >> 6, off = (ch & 63) * 4;
        int k = kbase + row;
        k = (k < 0) ? 0 : ((k > LKV_ - 1) ? LKV_ - 1 : k);
        *(float4*)(&A_lds[row * 256 + off]) =
            *(const float4*)(attnw + (size_t)(b * LKV_ + k) * 256 + off);
    }
    __syncthreads();

    const int d = t & 63;
    const int hg = t >> 6;
#pragma unroll
    for (int ql = 0; ql < 16; ++ql) {
        const int q = q0 + ql;
        const int j0 = q & 1;
        float acc[4] = {0.f, 0.f, 0.f, 0.f};
#pragma unroll
        for (int i = 0; i < SPAN / STRIDE; ++i) {
            const int kq = (q >> 1) - i;
            if (kq < 0) break;
            const int rr = kq - kbase;
#pragma unroll
            for (int hh = 0; hh < 4; ++hh) {
                const int h = hg * 4 + hh;
                acc[hh] += A_lds[rr * 256 + h * 16 + j0 + 2 * i] *
                           (float)Vs[rr * 1024 + h * 64 + d];
            }
        }
        f16* crow = ctx + (size_t)(b * LQ_ + q) * DMODEL;
#pragma unroll
        for (int hh = 0; hh < 4; ++hh) {
            const int h = hg * 4 + hh;
            crow[h * HD + d] = (f16)acc[hh];
        }
    }
}

// ---------------------------------------------------------------------------
extern "C" void kernel_launch(void* const* d_in, const int* in_sizes, int n_in,
                              void* d_out, int out_size, void* d_ws, size_t ws_size,
                              hipStream_t stream) {
    const float* q  = (const float*)d_in[0];
    const float* k  = (const float*)d_in[1];
    const float* v  = (const float*)d_in[2];
    const float* Wq = (const float*)d_in[3];
    const float* Wk = (const float*)d_in[4];
    const float* Wv = (const float*)d_in[5];
    const float* Wo = (const float*)d_in[6];
    float* out = (float*)d_out;

    const size_t NW = (size_t)DMODEL * DMODEL;

    char* p = (char*)d_ws;
    f16* WqT = (f16*)p; p += NW * 2;
    f16* WkT = (f16*)p; p += NW * 2;
    f16* WvT = (f16*)p; p += NW * 2;
    f16* WoT = (f16*)p; p += NW * 2;
    f16* Qh  = (f16*)p; p += NQ_ELEMS * 2;
    f16* Kh  = (f16*)p; p += NKV_ELEMS * 2;
    f16* Vh  = (f16*)p; p += NKV_ELEMS * 2;
    float* attnw = (float*)p; p += (size_t)B_ * LKV_ * NH * SPAN * 4;
    f16* ctxh = (f16*)p; p += NQ_ELEMS * 2;

    // 1) weight transposes only (q/k/v convert folded into gemm_qkv)
    transpose_all<<<dim3(1024), 256, 0, stream>>>(Wq, Wk, Wv, Wo,
                                                  WqT, WkT, WvT, WoT);

    // 2) Q/K/V projections, pipelined 256x256, 1 block/CU
    gemm_qkv<<<dim3(256), 512, 0, stream>>>(q, k, v, WqT, WkT, WvT, Qh, Kh, Vh);

    // 3) per-column masked scores + query-axis softmax
    attn_scores<<<dim3(LKV_ / 4, B_), 256, 0, stream>>>(Qh, Kh, attnw);

    // 4) per-query gather of weighted V
    ctx_gather<<<dim3(LQ_ / 16, B_), 256, 0, stream>>>(attnw, Vh, ctxh);

    // 5) output projection, pipelined 256x128
    gemm_out<<<dim3(256), 512, 0, stream>>>(ctxh, WoT, out);
}

// Round 2
// 243.966 us; speedup vs baseline: 1.0175x; 1.0175x over previous
//
#include <hip/hip_runtime.h>
#include <cstdint>
#include <cstddef>

// ---------------------------------------------------------------------------
// SparseMHADecoder: B=2, LQ=4096, LKV=2048, D=1024, H=16, d=64, span=16, stride=2
// R8: fix R7's register-spill (FETCH 47->108MB = scratch traffic).
//     - staging regs SINGLE-buffered (lifetime analysis: set loaded iter t is
//       consumed top of iter t+1; double-buffer was pure waste, -48 VGPR)
//     - COMPUTE streams afr per-m (preload bfr[NR] only): -24 transient VGPR
//     - qkv stays 256x256 (2x4 waves, acc 8x4=128 in AGPR; LDS/MFMA balanced)
//       budget: 128 AGPR + ~100-120 VGPR < 256 cap -> no spill
//     - gemm_out 256x128 (4x2 waves, acc 4x4=64), 256 blocks = 1/CU
// R7 carried: distance-2 pipeline, double-buffered LDS, ONE lgkmcnt+s_barrier
//     per K-tile, prefetch in flight across barriers, setprio on MFMA.
// R6 carried: f32->f16 A-convert folded into qkv staging.
// R5 carried: XOR chunk swizzle (bank-conflict counter = 0 both rounds).
// ---------------------------------------------------------------------------

typedef _Float16 f16;
typedef _Float16 f16x8 __attribute__((ext_vector_type(8)));
typedef float v4f __attribute__((ext_vector_type(4)));

#define B_  2
#define LQ_ 4096
#define LKV_ 2048
#define DMODEL 1024
#define NH 16
#define HD 64
#define SPAN 16
#define STRIDE 2

#define NQ_ELEMS  ((size_t)B_ * LQ_ * DMODEL)   // 8388608
#define NKV_ELEMS ((size_t)B_ * LKV_ * DMODEL)  // 4194304

// ------------- prep: 4 weight transposes, Wt[n][k] = (f16)W[k][n] ------------
__global__ __launch_bounds__(256)
void transpose_all(const float* __restrict__ W0, const float* __restrict__ W1,
                   const float* __restrict__ W2, const float* __restrict__ W3,
                   f16* __restrict__ T0, f16* __restrict__ T1,
                   f16* __restrict__ T2, f16* __restrict__ T3) {
    const int t = threadIdx.x;
    const int bid = blockIdx.x;             // 1024 = 16x16 tiles x 4 weights
    const int z = bid >> 8, rem = bid & 255;
    const int bx = rem & 15, byy = rem >> 4;
    const float* W;
    f16* Wt;
    switch (z) {
        case 0: W = W0; Wt = T0; break;
        case 1: W = W1; Wt = T1; break;
        case 2: W = W2; Wt = T2; break;
        default: W = W3; Wt = T3; break;
    }
    __shared__ float tile[64][65];
    const int r0 = byy * 64, c0 = bx * 64;
    const int tx = t & 63, ty = t >> 6;     // (64,4)
    for (int i = ty; i < 64; i += 4)
        tile[i][tx] = W[(long)(r0 + i) * DMODEL + c0 + tx];
    __syncthreads();
    for (int i = ty; i < 64; i += 4)
        Wt[(long)(c0 + i) * DMODEL + r0 + tx] = (f16)tile[tx][i];
}

// ---------------------------------------------------------------------------
// Pipelined fp16 GEMM: C[m][n] = sum_k A[m][k] * Bt[n][k]
// BM=256, BN cols, BK=64, 512 threads = 8 waves (WM x WN).
// LDS double-buffered; ONE lgkmcnt(0)+s_barrier per K-tile.
// Distance-2 pipeline with SINGLE staging reg set:
//   iter t: WRITE(t+1) <- regs loaded at iter t-1 (vmcnt satisfied long ago)
//           LOAD(t+2)  -> same regs (WAR, in-order), in flight across barrier
//           COMPUTE(t) from LDS buf t&1
// Swizzle: LDS chunk c of row r holds global chunk c^(r&7) (involution).
// ---------------------------------------------------------------------------
template <bool A_F32, bool OUT_F32, int BN, int WM, int WN, int MR, int NR>
__device__ __forceinline__ void gemm_pipe(const void* __restrict__ Av,
                                          const f16* __restrict__ Bt,
                                          void* __restrict__ Cv,
                                          int rowTile, int colTile) {
    constexpr int BM = 256, BK = 64, K = DMODEL, N = DMODEL, NT = K / BK;
    static_assert(WM * MR * 16 == BM, "BM decomposition");
    static_assert(WN * NR * 16 == BN, "BN decomposition");
    constexpr int LA = BM * BK;             // f16 elems per A tile (16384)
    constexpr int LB = BN * BK;
    constexpr int LT = LA + LB;
    __shared__ f16 lds[2 * LT];             // qkv: 128 KB, out: 96 KB

    const int t = threadIdx.x;              // 512
    const int lane = t & 63, w = t >> 6;
    const int wm = w / WN, wn = w % WN;
    const int qrow = lane & 15, quad = lane >> 4;
    const long rowBase = (long)rowTile * BM;
    const long colBase = (long)colTile * BN;

    // ---- staging geometry (A: 2 thr/row covering 32 k-elems each) ----
    const int arow = t >> 1, ah = t & 1;
    constexpr int TPRB = 512 / BN;          // B threads per row (2 or 4)
    constexpr int CPTB = 8 / TPRB;          // B 8-f16 chunks per thread
    const int brow = t / TPRB, bsub = t % TPRB;

    const float* gAf = (const float*)Av + (rowBase + arow) * (long)K + ah * 32;
    const f16*   gAh = (const f16*)Av + (rowBase + arow) * (long)K + ah * 32;
    const f16*   gB  = Bt + (colBase + brow) * (long)K + bsub * (CPTB * 8);

    // LDS element offsets (swizzled; bank-conflict counter = 0, R5/R7)
    int offA[4], offB[CPTB];
#pragma unroll
    for (int j = 0; j < 4; ++j)
        offA[j] = arow * BK + (((ah * 4 + j) ^ (arow & 7)) * 8);
#pragma unroll
    for (int j = 0; j < CPTB; ++j)
        offB[j] = LA + brow * BK + (((bsub * CPTB + j) ^ (brow & 7)) * 8);

    int offAf[MR], offBf[NR];
#pragma unroll
    for (int m = 0; m < MR; ++m) offAf[m] = (wm * (MR * 16) + m * 16 + qrow) * BK;
#pragma unroll
    for (int n = 0; n < NR; ++n) offBf[n] = LA + (wn * (NR * 16) + n * 16 + qrow) * BK;

    // SINGLE staging register set (distance-2 lifetime never overlaps itself)
    float4 ra[8];                           // A_F32 path: 32 VGPR
    f16x8  rah[4];                          // f16 path:   16 VGPR
    f16x8  rb[CPTB];
    v4f acc[MR][NR] = {};

    auto LOAD = [&](int tt) {
        if constexpr (A_F32) {
#pragma unroll
            for (int j = 0; j < 8; ++j)
                ra[j] = *(const float4*)(gAf + tt * BK + 4 * j);
        } else {
#pragma unroll
            for (int j = 0; j < 4; ++j)
                rah[j] = *(const f16x8*)(gAh + tt * BK + 8 * j);
        }
#pragma unroll
        for (int j = 0; j < CPTB; ++j)
            rb[j] = *(const f16x8*)(gB + tt * BK + 8 * j);
    };

    auto WRITE = [&](int tt) {
        f16* lp = &lds[(tt & 1) * LT];
        if constexpr (A_F32) {
#pragma unroll
            for (int j = 0; j < 4; ++j) {
                float4 lo = ra[2 * j], hi = ra[2 * j + 1];
                f16x8 o = {(f16)lo.x, (f16)lo.y, (f16)lo.z, (f16)lo.w,
                           (f16)hi.x, (f16)hi.y, (f16)hi.z, (f16)hi.w};
                *(f16x8*)(lp + offA[j]) = o;
            }
        } else {
#pragma unroll
            for (int j = 0; j < 4; ++j)
                *(f16x8*)(lp + offA[j]) = rah[j];
        }
#pragma unroll
        for (int j = 0; j < CPTB; ++j)
            *(f16x8*)(lp + offB[j]) = rb[j];
    };

    auto COMPUTE = [&](int tt) {
        const f16* lp = &lds[(tt & 1) * LT];
#pragma unroll
        for (int s = 0; s < 2; ++s) {
            const int xk = ((s * 4 + quad) ^ (qrow & 7)) * 8;
            f16x8 bfr[NR];
#pragma unroll
            for (int n = 0; n < NR; ++n) bfr[n] = *(const f16x8*)(lp + offBf[n] + xk);
            __builtin_amdgcn_s_setprio(1);
#pragma unroll
            for (int m = 0; m < MR; ++m) {      // stream afr: low transient regs
                f16x8 afr = *(const f16x8*)(lp + offAf[m] + xk);
#pragma unroll
                for (int n = 0; n < NR; ++n)
                    acc[m][n] = __builtin_amdgcn_mfma_f32_16x16x32_f16(
                        afr, bfr[n], acc[m][n], 0, 0, 0);
            }
            __builtin_amdgcn_s_setprio(0);
        }
    };

    // ---- prologue ----
    LOAD(0);
    WRITE(0);                // compiler inserts counted vmcnt for ra/rb uses
    LOAD(1);                 // in flight across prologue barrier
    asm volatile("s_waitcnt lgkmcnt(0)" ::: "memory");
    __builtin_amdgcn_s_barrier();
    asm volatile("" ::: "memory");

    // ---- main loop: fully unrolled, one barrier per K-tile ----
#pragma unroll
    for (int tt = 0; tt < NT; ++tt) {
        if (tt + 1 < NT) WRITE(tt + 1);     // regs loaded at iter tt-1
        if (tt + 2 < NT) LOAD(tt + 2);      // stays in flight across barrier
        COMPUTE(tt);
        if (tt + 1 < NT) {
            asm volatile("s_waitcnt lgkmcnt(0)" ::: "memory");
            __builtin_amdgcn_s_barrier();
            asm volatile("" ::: "memory");
        }
    }

    // ---- epilogue: C/D layout (m89-verified): row = quad*4 + r, col = qrow --
#pragma unroll
    for (int m = 0; m < MR; ++m)
#pragma unroll
        for (int n = 0; n < NR; ++n) {
            const long col = colBase + wn * (NR * 16) + n * 16 + qrow;
#pragma unroll
            for (int r = 0; r < 4; ++r) {
                const long row = rowBase + wm * (MR * 16) + m * 16 + quad * 4 + r;
                if constexpr (OUT_F32)
                    ((float*)Cv)[row * (long)N + col] = acc[m][n][r];
                else
                    ((f16*)Cv)[row * (long)N + col] = (f16)acc[m][n][r];
            }
        }
}

// Fused Q/K/V projection from ORIGINAL f32 inputs. 256x256 tile -> 256 blocks
// (Q:128, K:64, V:64) x 512 thr = exactly 1 block/CU, one round. XCD-grouped.
__global__ __launch_bounds__(512)
void gemm_qkv(const float* __restrict__ q, const float* __restrict__ k,
              const float* __restrict__ v, const f16* __restrict__ WqT,
              const f16* __restrict__ WkT, const f16* __restrict__ WvT,
              f16* __restrict__ Qh, f16* __restrict__ Kh, f16* __restrict__ Vh) {
    const int id = (blockIdx.x & 7) * 32 + (blockIdx.x >> 3);  // bijective, 256
    const float* A; const f16* Bt; f16* C; int rt, ct;
    if (id < 128)      { A = q; Bt = WqT; C = Qh; ct = id >> 5; rt = id & 31; }
    else if (id < 192) { const int g = id - 128; A = k; Bt = WkT; C = Kh; ct = g >> 4; rt = g & 15; }
    else               { const int g = id - 192; A = v; Bt = WvT; C = Vh; ct = g >> 4; rt = g & 15; }
    gemm_pipe<true, false, 256, 2, 4, 8, 4>((const void*)A, Bt, (void*)C, rt, ct);
}

// Output projection (f16 in, f32 out). 256x128 tile -> 32x8 = 256 blocks.
__global__ __launch_bounds__(512)
void gemm_out(const f16* __restrict__ A, const f16* __restrict__ Bt,
              float* __restrict__ C) {
    const int id = (blockIdx.x & 7) * 32 + (blockIdx.x >> 3);
    const int ct = id >> 5, rt = id & 31;
    gemm_pipe<false, true, 128, 4, 2, 4, 4>((const void*)A, Bt, (void*)C, rt, ct);
}

// -------- per-column scores + softmax over the 16 valid query rows ----------
__global__ __launch_bounds__(256)
void attn_scores(const f16* __restrict__ Q, const f16* __restrict__ Km,
                 float* __restrict__ attnw) {
    const int c0 = blockIdx.x * 4, b = blockIdx.y;
    const int t = threadIdx.x;
    __shared__ f16 Qs[24 * 1032];   // rows 0..21 used; 49.5 KB
    __shared__ f16 Ks[4 * 1032];    // 8.25 KB

#pragma unroll
    for (int it = 0; it < 12; ++it) {
        const int ch = t + 256 * it;        // 24 rows x 128 chunks
        const int row = ch >> 7, off = (ch & 127) * 8;
        int qq = 2 * c0 + row;
        if (qq > LQ_ - 1) qq = LQ_ - 1;     // clamp staging; masked in score
        f16x8 x = *(const f16x8*)(Q + (size_t)(b * LQ_ + qq) * DMODEL + off);
        const int h = off >> 6, bb = (off >> 3) & 7;
        *(f16x8*)(&Qs[row * 1032 + h * 64 + ((bb + h) & 7) * 8]) = x;
    }
#pragma unroll
    for (int it = 0; it < 2; ++it) {
        const int ch = t + 256 * it;        // 4 rows x 128 chunks
        const int row = ch >> 7, off = (ch & 127) * 8;
        f16x8 x = *(const f16x8*)(Km + (size_t)(b * LKV_ + c0 + row) * DMODEL + off);
        const int h = off >> 6, bb = (off >> 3) & 7;
        *(f16x8*)(&Ks[row * 1032 + h * 64 + ((bb + h) & 7) * 8]) = x;
    }
    __syncthreads();

    const int h = t >> 4, j = t & 15;
#pragma unroll
    for (int ci = 0; ci < 4; ++ci) {
        const int c = c0 + ci;
        const int q = STRIDE * c + j;
        const int row = 2 * ci + j;
        float a = 0.f;
#pragma unroll
        for (int bb = 0; bb < 8; ++bb) {
            const int off = h * 64 + ((bb + h) & 7) * 8;
            f16x8 qv = *(const f16x8*)(&Qs[row * 1032 + off]);
            f16x8 kv = *(const f16x8*)(&Ks[ci * 1032 + off]);  // wave-broadcast
#pragma unroll
            for (int u = 0; u < 8; ++u) a += (float)qv[u] * (float)kv[u];
        }
        float s = (q < LQ_) ? a : -1e30f;
        float m = s;
#pragma unroll
        for (int o = 1; o < 16; o <<= 1) m = fmaxf(m, __shfl_xor(m, o, 64));
        float p = (q < LQ_) ? __expf(s - m) : 0.f;
        float sum = p;
#pragma unroll
        for (int o = 1; o < 16; o <<= 1) sum += __shfl_xor(sum, o, 64);
        attnw[(size_t)((b * LKV_ + c) * NH + h) * SPAN + j] = p / sum;
    }
}

// ---- ctx[b,q,h,:] = sum_i attn[b, q/2-i, h, (q&1)+2i] * V[b, q/2-i, h, :] ----
__global__ __launch_bounds__(256)
void ctx_gather(const float* __restrict__ attnw, const f16* __restrict__ V,
                f16* __restrict__ ctx) {
    const int q0 = blockIdx.x * 16, b = blockIdx.y;
    const int t = threadIdx.x;
    const int kbase = (q0 >> 1) - 7;
    __shared__ f16 Vs[16 * 1024];     // 32 KB
    __shared__ float A_lds[16 * 256]; // 16 KB

#pragma unroll
    for (int it = 0; it < 8; ++it) {
        const int ch = t + 256 * it;       // 16 rows x 128 chunks
        const int row = ch >> 7, off = (ch & 127) * 8;
        int k = kbase + row;
        k = (k < 0) ? 0 : ((k > LKV_ - 1) ? LKV_ - 1 : k);
        *(f16x8*)(&Vs[row * 1024 + off]) =
            *(const f16x8*)(V + (size_t)(b * LKV_ + k) * DMODEL + off);
    }
#pragma unroll
    for (int it = 0; it < 4; ++it) {
        const int ch = t + 256 * it;       // 16 rows x 64 chunks of 4 f32
        const int row = ch >> 6, off = (ch & 63) * 4;
        int k = kbase + row;
        k = (k < 0) ? 0 : ((k > LKV_ - 1) ? LKV_ - 1 : k);
        *(float4*)(&A_lds[row * 256 + off]) =
            *(const float4*)(attnw + (size_t)(b * LKV_ + k) * 256 + off);
    }
    __syncthreads();

    const int d = t & 63;
    const int hg = t >> 6;
#pragma unroll
    for (int ql = 0; ql < 16; ++ql) {
        const int q = q0 + ql;
        const int j0 = q & 1;
        float acc[4] = {0.f, 0.f, 0.f, 0.f};
#pragma unroll
        for (int i = 0; i < SPAN / STRIDE; ++i) {
            const int kq = (q >> 1) - i;
            if (kq < 0) break;
            const int rr = kq - kbase;
#pragma unroll
            for (int hh = 0; hh < 4; ++hh) {
                const int h = hg * 4 + hh;
                acc[hh] += A_lds[rr * 256 + h * 16 + j0 + 2 * i] *
                           (float)Vs[rr * 1024 + h * 64 + d];
            }
        }
        f16* crow = ctx + (size_t)(b * LQ_ + q) * DMODEL;
#pragma unroll
        for (int hh = 0; hh < 4; ++hh) {
            const int h = hg * 4 + hh;
            crow[h * HD + d] = (f16)acc[hh];
        }
    }
}

// ---------------------------------------------------------------------------
extern "C" void kernel_launch(void* const* d_in, const int* in_sizes, int n_in,
                              void* d_out, int out_size, void* d_ws, size_t ws_size,
                              hipStream_t stream) {
    const float* q  = (const float*)d_in[0];
    const float* k  = (const float*)d_in[1];
    const float* v  = (const float*)d_in[2];
    const float* Wq = (const float*)d_in[3];
    const float* Wk = (const float*)d_in[4];
    const float* Wv = (const float*)d_in[5];
    const float* Wo = (const float*)d_in[6];
    float* out = (float*)d_out;

    const size_t NW = (size_t)DMODEL * DMODEL;

    char* p = (char*)d_ws;
    f16* WqT = (f16*)p; p += NW * 2;
    f16* WkT = (f16*)p; p += NW * 2;
    f16* WvT = (f16*)p; p += NW * 2;
    f16* WoT = (f16*)p; p += NW * 2;
    f16* Qh  = (f16*)p; p += NQ_ELEMS * 2;
    f16* Kh  = (f16*)p; p += NKV_ELEMS * 2;
    f16* Vh  = (f16*)p; p += NKV_ELEMS * 2;
    float* attnw = (float*)p; p += (size_t)B_ * LKV_ * NH * SPAN * 4;
    f16* ctxh = (f16*)p; p += NQ_ELEMS * 2;

    // 1) weight transposes only (q/k/v convert folded into gemm_qkv)
    transpose_all<<<dim3(1024), 256, 0, stream>>>(Wq, Wk, Wv, Wo,
                                                  WqT, WkT, WvT, WoT);

    // 2) Q/K/V projections, pipelined 256x256, 1 block/CU
    gemm_qkv<<<dim3(256), 512, 0, stream>>>(q, k, v, WqT, WkT, WvT, Qh, Kh, Vh);

    // 3) per-column masked scores + query-axis softmax
    attn_scores<<<dim3(LKV_ / 4, B_), 256, 0, stream>>>(Qh, Kh, attnw);

    // 4) per-query gather of weighted V
    ctx_gather<<<dim3(LQ_ / 16, B_), 256, 0, stream>>>(attnw, Vh, ctxh);

    // 5) output projection, pipelined 256x128
    gemm_out<<<dim3(256), 512, 0, stream>>>(ctxh, WoT, out);
}

// Round 4
// 221.924 us; speedup vs baseline: 1.1185x; 1.0993x over previous
//
#include <hip/hip_runtime.h>
#include <cstdint>
#include <cstddef>

// ---------------------------------------------------------------------------
// SparseMHADecoder: B=2, LQ=4096, LKV=2048, D=1024, H=16, d=64, span=16, stride=2
// R10 = R9 resubmitted verbatim (R9 bench died to a container-acquire infra
//       failure; OOB/barrier/coverage audits found no kernel defect).
// R9: fix R8's wave-scattered staging loads (the real latency bottleneck:
//     2-thr/row geometry made every staging load touch ~64 cache lines).
//     - staging now g=t>>3,l=t&7: each 8-lane group reads a contiguous
//       128-256B run of ONE row (R6's proven coalesced pattern), thread
//       covers rows g+64i. XOR swizzle preserved: (g+64i)&7 == g&7.
//     - XCD grouping now shares the A-panel (32MB operand) per XCD:
//       rt = id>>2, ct = id&3 per projection (weights are only 2MB).
// R8 carried: single staging reg set (no spill, WRITE_SIZE==output exactly).
// R7 carried: distance-2 pipeline, double-buffered LDS, ONE lgkmcnt+s_barrier
//     per K-tile, prefetch in flight across barriers, setprio on MFMA.
// R6 carried: f32->f16 A-convert folded into qkv staging.
// R5 carried: XOR chunk swizzle (bank-conflict counter = 0 all rounds).
// ---------------------------------------------------------------------------

typedef _Float16 f16;
typedef _Float16 f16x8 __attribute__((ext_vector_type(8)));
typedef float v4f __attribute__((ext_vector_type(4)));

#define B_  2
#define LQ_ 4096
#define LKV_ 2048
#define DMODEL 1024
#define NH 16
#define HD 64
#define SPAN 16
#define STRIDE 2

#define NQ_ELEMS  ((size_t)B_ * LQ_ * DMODEL)   // 8388608
#define NKV_ELEMS ((size_t)B_ * LKV_ * DMODEL)  // 4194304

// ------------- prep: 4 weight transposes, Wt[n][k] = (f16)W[k][n] ------------
__global__ __launch_bounds__(256)
void transpose_all(const float* __restrict__ W0, const float* __restrict__ W1,
                   const float* __restrict__ W2, const float* __restrict__ W3,
                   f16* __restrict__ T0, f16* __restrict__ T1,
                   f16* __restrict__ T2, f16* __restrict__ T3) {
    const int t = threadIdx.x;
    const int bid = blockIdx.x;             // 1024 = 16x16 tiles x 4 weights
    const int z = bid >> 8, rem = bid & 255;
    const int bx = rem & 15, byy = rem >> 4;
    const float* W;
    f16* Wt;
    switch (z) {
        case 0: W = W0; Wt = T0; break;
        case 1: W = W1; Wt = T1; break;
        case 2: W = W2; Wt = T2; break;
        default: W = W3; Wt = T3; break;
    }
    __shared__ float tile[64][65];
    const int r0 = byy * 64, c0 = bx * 64;
    const int tx = t & 63, ty = t >> 6;     // (64,4)
    for (int i = ty; i < 64; i += 4)
        tile[i][tx] = W[(long)(r0 + i) * DMODEL + c0 + tx];
    __syncthreads();
    for (int i = ty; i < 64; i += 4)
        Wt[(long)(c0 + i) * DMODEL + r0 + tx] = (f16)tile[tx][i];
}

// ---------------------------------------------------------------------------
// Pipelined fp16 GEMM: C[m][n] = sum_k A[m][k] * Bt[n][k]
// BM=256, BN cols, BK=64, 512 threads = 8 waves (WM x WN).
// LDS double-buffered; ONE lgkmcnt(0)+s_barrier per K-tile.
// Distance-2 pipeline, SINGLE staging reg set (lifetimes never overlap):
//   iter t: WRITE(t+1) <- regs loaded at iter t-1 (vmcnt long satisfied)
//           LOAD(t+2)  -> same regs (WAR, in-order), in flight across barrier
//           COMPUTE(t) from LDS buf t&1
// Staging geometry (coalesced): l = t&7 (chunk), g = t>>3 (0..63);
//   thread covers chunk l of rows g+64i. Per instruction each 8-lane group
//   reads a contiguous run of one row; LDS chunk c of row r holds global
//   chunk c^(r&7), and (g+64i)&7 == g&7 so the XOR is thread-constant.
// ---------------------------------------------------------------------------
template <bool A_F32, bool OUT_F32, int BN, int WM, int WN, int MR, int NR>
__device__ __forceinline__ void gemm_pipe(const void* __restrict__ Av,
                                          const f16* __restrict__ Bt,
                                          void* __restrict__ Cv,
                                          int rowTile, int colTile) {
    constexpr int BM = 256, BK = 64, K = DMODEL, N = DMODEL, NT = K / BK;
    static_assert(WM * MR * 16 == BM, "BM decomposition");
    static_assert(WN * NR * 16 == BN, "BN decomposition");
    constexpr int LA = BM * BK;             // f16 elems per A tile (16384)
    constexpr int LB = BN * BK;
    constexpr int LT = LA + LB;
    constexpr int NBI = BN / 64;            // B row-passes (4 or 2)
    __shared__ f16 lds[2 * LT];             // qkv: 128 KB, out: 96 KB

    const int t = threadIdx.x;              // 512
    const int lane = t & 63, w = t >> 6;
    const int wm = w / WN, wn = w % WN;
    const int qrow = lane & 15, quad = lane >> 4;
    const long rowBase = (long)rowTile * BM;
    const long colBase = (long)colTile * BN;

    // ---- staging geometry: chunk l of rows g+64i ----
    const int l = t & 7, g = t >> 3;
    const int lsw = (l ^ (g & 7)) * 8;      // thread-constant swizzled chunk

    const float* gAf = (const float*)Av + (rowBase + g) * (long)K + l * 8;
    const f16*   gAh = (const f16*)Av + (rowBase + g) * (long)K + l * 8;
    const f16*   gB  = Bt + (colBase + g) * (long)K + l * 8;

    int offA[4], offB[NBI];
#pragma unroll
    for (int i = 0; i < 4; ++i) offA[i] = (g + 64 * i) * BK + lsw;
#pragma unroll
    for (int i = 0; i < NBI; ++i) offB[i] = LA + (g + 64 * i) * BK + lsw;

    int offAf[MR], offBf[NR];
#pragma unroll
    for (int m = 0; m < MR; ++m) offAf[m] = (wm * (MR * 16) + m * 16 + qrow) * BK;
#pragma unroll
    for (int n = 0; n < NR; ++n) offBf[n] = LA + (wn * (NR * 16) + n * 16 + qrow) * BK;

    // SINGLE staging register set (distance-2 lifetime never overlaps itself)
    float4 ra[8];                           // A_F32 path: 32 VGPR
    f16x8  rah[4];                          // f16 path:   16 VGPR
    f16x8  rb[NBI];
    v4f acc[MR][NR] = {};

    auto LOAD = [&](int tt) {
        if constexpr (A_F32) {
#pragma unroll
            for (int i = 0; i < 4; ++i) {
                ra[2 * i]     = *(const float4*)(gAf + (long)i * 64 * K + tt * BK);
                ra[2 * i + 1] = *(const float4*)(gAf + (long)i * 64 * K + tt * BK + 4);
            }
        } else {
#pragma unroll
            for (int i = 0; i < 4; ++i)
                rah[i] = *(const f16x8*)(gAh + (long)i * 64 * K + tt * BK);
        }
#pragma unroll
        for (int i = 0; i < NBI; ++i)
            rb[i] = *(const f16x8*)(gB + (long)i * 64 * K + tt * BK);
    };

    auto WRITE = [&](int tt) {
        f16* lp = &lds[(tt & 1) * LT];
        if constexpr (A_F32) {
#pragma unroll
            for (int i = 0; i < 4; ++i) {
                float4 lo = ra[2 * i], hi = ra[2 * i + 1];
                f16x8 o = {(f16)lo.x, (f16)lo.y, (f16)lo.z, (f16)lo.w,
                           (f16)hi.x, (f16)hi.y, (f16)hi.z, (f16)hi.w};
                *(f16x8*)(lp + offA[i]) = o;
            }
        } else {
#pragma unroll
            for (int i = 0; i < 4; ++i)
                *(f16x8*)(lp + offA[i]) = rah[i];
        }
#pragma unroll
        for (int i = 0; i < NBI; ++i)
            *(f16x8*)(lp + offB[i]) = rb[i];
    };

    auto COMPUTE = [&](int tt) {
        const f16* lp = &lds[(tt & 1) * LT];
#pragma unroll
        for (int s = 0; s < 2; ++s) {
            const int xk = ((s * 4 + quad) ^ (qrow & 7)) * 8;
            f16x8 bfr[NR];
#pragma unroll
            for (int n = 0; n < NR; ++n) bfr[n] = *(const f16x8*)(lp + offBf[n] + xk);
            __builtin_amdgcn_s_setprio(1);
#pragma unroll
            for (int m = 0; m < MR; ++m) {      // stream afr: low transient regs
                f16x8 afr = *(const f16x8*)(lp + offAf[m] + xk);
#pragma unroll
                for (int n = 0; n < NR; ++n)
                    acc[m][n] = __builtin_amdgcn_mfma_f32_16x16x32_f16(
                        afr, bfr[n], acc[m][n], 0, 0, 0);
            }
            __builtin_amdgcn_s_setprio(0);
        }
    };

    // ---- prologue ----
    LOAD(0);
    WRITE(0);                // compiler inserts counted vmcnt for ra/rb uses
    LOAD(1);                 // in flight across prologue barrier
    asm volatile("s_waitcnt lgkmcnt(0)" ::: "memory");
    __builtin_amdgcn_s_barrier();
    asm volatile("" ::: "memory");

    // ---- main loop: fully unrolled, one barrier per K-tile ----
#pragma unroll
    for (int tt = 0; tt < NT; ++tt) {
        if (tt + 1 < NT) WRITE(tt + 1);     // regs loaded at iter tt-1
        if (tt + 2 < NT) LOAD(tt + 2);      // stays in flight across barrier
        COMPUTE(tt);
        if (tt + 1 < NT) {
            asm volatile("s_waitcnt lgkmcnt(0)" ::: "memory");
            __builtin_amdgcn_s_barrier();
            asm volatile("" ::: "memory");
        }
    }

    // ---- epilogue: C/D layout (m89-verified): row = quad*4 + r, col = qrow --
#pragma unroll
    for (int m = 0; m < MR; ++m)
#pragma unroll
        for (int n = 0; n < NR; ++n) {
            const long col = colBase + wn * (NR * 16) + n * 16 + qrow;
#pragma unroll
            for (int r = 0; r < 4; ++r) {
                const long row = rowBase + wm * (MR * 16) + m * 16 + quad * 4 + r;
                if constexpr (OUT_F32)
                    ((float*)Cv)[row * (long)N + col] = acc[m][n][r];
                else
                    ((f16*)Cv)[row * (long)N + col] = (f16)acc[m][n][r];
            }
        }
}

// Fused Q/K/V projection from ORIGINAL f32 inputs. 256x256 tile -> 256 blocks
// (Q:128, K:64, V:64) x 512 thr = exactly 1 block/CU, one round.
// XCD grouping shares the A row-panel (the 32MB operand); each XCD re-reads
// A rows from its own L2, weights (2MB) replicate cheaply.
__global__ __launch_bounds__(512)
void gemm_qkv(const float* __restrict__ q, const float* __restrict__ k,
              const float* __restrict__ v, const f16* __restrict__ WqT,
              const f16* __restrict__ WkT, const f16* __restrict__ WvT,
              f16* __restrict__ Qh, f16* __restrict__ Kh, f16* __restrict__ Vh) {
    const int id = (blockIdx.x & 7) * 32 + (blockIdx.x >> 3);  // bijective, 256
    const float* A; const f16* Bt; f16* C; int rt, ct;
    if (id < 128)      { A = q; Bt = WqT; C = Qh; rt = id >> 2; ct = id & 3; }
    else if (id < 192) { const int g = id - 128; A = k; Bt = WkT; C = Kh; rt = g >> 2; ct = g & 3; }
    else               { const int g = id - 192; A = v; Bt = WvT; C = Vh; rt = g >> 2; ct = g & 3; }
    gemm_pipe<true, false, 256, 2, 4, 8, 4>((const void*)A, Bt, (void*)C, rt, ct);
}

// Output projection (f16 in, f32 out). 256x128 tile -> 32x8 = 256 blocks.
__global__ __launch_bounds__(512)
void gemm_out(const f16* __restrict__ A, const f16* __restrict__ Bt,
              float* __restrict__ C) {
    const int id = (blockIdx.x & 7) * 32 + (blockIdx.x >> 3);
    const int rt = id >> 3, ct = id & 7;    // A-panel shared per XCD
    gemm_pipe<false, true, 128, 4, 2, 4, 4>((const void*)A, Bt, (void*)C, rt, ct);
}

// -------- per-column scores + softmax over the 16 valid query rows ----------
__global__ __launch_bounds__(256)
void attn_scores(const f16* __restrict__ Q, const f16* __restrict__ Km,
                 float* __restrict__ attnw) {
    const int c0 = blockIdx.x * 4, b = blockIdx.y;
    const int t = threadIdx.x;
    __shared__ f16 Qs[24 * 1032];   // rows 0..21 used; 49.5 KB
    __shared__ f16 Ks[4 * 1032];    // 8.25 KB

#pragma unroll
    for (int it = 0; it < 12; ++it) {
        const int ch = t + 256 * it;        // 24 rows x 128 chunks
        const int row = ch >> 7, off = (ch & 127) * 8;
        int qq = 2 * c0 + row;
        if (qq > LQ_ - 1) qq = LQ_ - 1;     // clamp staging; masked in score
        f16x8 x = *(const f16x8*)(Q + (size_t)(b * LQ_ + qq) * DMODEL + off);
        const int h = off >> 6, bb = (off >> 3) & 7;
        *(f16x8*)(&Qs[row * 1032 + h * 64 + ((bb + h) & 7) * 8]) = x;
    }
#pragma unroll
    for (int it = 0; it < 2; ++it) {
        const int ch = t + 256 * it;        // 4 rows x 128 chunks
        const int row = ch >> 7, off = (ch & 127) * 8;
        f16x8 x = *(const f16x8*)(Km + (size_t)(b * LKV_ + c0 + row) * DMODEL + off);
        const int h = off >> 6, bb = (off >> 3) & 7;
        *(f16x8*)(&Ks[row * 1032 + h * 64 + ((bb + h) & 7) * 8]) = x;
    }
    __syncthreads();

    const int h = t >> 4, j = t & 15;
#pragma unroll
    for (int ci = 0; ci < 4; ++ci) {
        const int c = c0 + ci;
        const int q = STRIDE * c + j;
        const int row = 2 * ci + j;
        float a = 0.f;
#pragma unroll
        for (int bb = 0; bb < 8; ++bb) {
            const int off = h * 64 + ((bb + h) & 7) * 8;
            f16x8 qv = *(const f16x8*)(&Qs[row * 1032 + off]);
            f16x8 kv = *(const f16x8*)(&Ks[ci * 1032 + off]);  // wave-broadcast
#pragma unroll
            for (int u = 0; u < 8; ++u) a += (float)qv[u] * (float)kv[u];
        }
        float s = (q < LQ_) ? a : -1e30f;
        float m = s;
#pragma unroll
        for (int o = 1; o < 16; o <<= 1) m = fmaxf(m, __shfl_xor(m, o, 64));
        float p = (q < LQ_) ? __expf(s - m) : 0.f;
        float sum = p;
#pragma unroll
        for (int o = 1; o < 16; o <<= 1) sum += __shfl_xor(sum, o, 64);
        attnw[(size_t)((b * LKV_ + c) * NH + h) * SPAN + j] = p / sum;
    }
}

// ---- ctx[b,q,h,:] = sum_i attn[b, q/2-i, h, (q&1)+2i] * V[b, q/2-i, h, :] ----
__global__ __launch_bounds__(256)
void ctx_gather(const float* __restrict__ attnw, const f16* __restrict__ V,
                f16* __restrict__ ctx) {
    const int q0 = blockIdx.x * 16, b = blockIdx.y;
    const int t = threadIdx.x;
    const int kbase = (q0 >> 1) - 7;
    __shared__ f16 Vs[16 * 1024];     // 32 KB
    __shared__ float A_lds[16 * 256]; // 16 KB

#pragma unroll
    for (int it = 0; it < 8; ++it) {
        const int ch = t + 256 * it;       // 16 rows x 128 chunks
        const int row = ch >> 7, off = (ch & 127) * 8;
        int k = kbase + row;
        k = (k < 0) ? 0 : ((k > LKV_ - 1) ? LKV_ - 1 : k);
        *(f16x8*)(&Vs[row * 1024 + off]) =
            *(const f16x8*)(V + (size_t)(b * LKV_ + k) * DMODEL + off);
    }
#pragma unroll
    for (int it = 0; it < 4; ++it) {
        const int ch = t + 256 * it;       // 16 rows x 64 chunks of 4 f32
        const int row = ch >> 6, off = (ch & 63) * 4;
        int k = kbase + row;
        k = (k < 0) ? 0 : ((k > LKV_ - 1) ? LKV_ - 1 : k);
        *(float4*)(&A_lds[row * 256 + off]) =
            *(const float4*)(attnw + (size_t)(b * LKV_ + k) * 256 + off);
    }
    __syncthreads();

    const int d = t & 63;
    const int hg = t >> 6;
#pragma unroll
    for (int ql = 0; ql < 16; ++ql) {
        const int q = q0 + ql;
        const int j0 = q & 1;
        float acc[4] = {0.f, 0.f, 0.f, 0.f};
#pragma unroll
        for (int i = 0; i < SPAN / STRIDE; ++i) {
            const int kq = (q >> 1) - i;
            if (kq < 0) break;
            const int rr = kq - kbase;
#pragma unroll
            for (int hh = 0; hh < 4; ++hh) {
                const int h = hg * 4 + hh;
                acc[hh] += A_lds[rr * 256 + h * 16 + j0 + 2 * i] *
                           (float)Vs[rr * 1024 + h * 64 + d];
            }
        }
        f16* crow = ctx + (size_t)(b * LQ_ + q) * DMODEL;
#pragma unroll
        for (int hh = 0; hh < 4; ++hh) {
            const int h = hg * 4 + hh;
            crow[h * HD + d] = (f16)acc[hh];
        }
    }
}

// ---------------------------------------------------------------------------
extern "C" void kernel_launch(void* const* d_in, const int* in_sizes, int n_in,
                              void* d_out, int out_size, void* d_ws, size_t ws_size,
                              hipStream_t stream) {
    const float* q  = (const float*)d_in[0];
    const float* k  = (const float*)d_in[1];
    const float* v  = (const float*)d_in[2];
    const float* Wq = (const float*)d_in[3];
    const float* Wk = (const float*)d_in[4];
    const float* Wv = (const float*)d_in[5];
    const float* Wo = (const float*)d_in[6];
    float* out = (float*)d_out;

    const size_t NW = (size_t)DMODEL * DMODEL;

    char* p = (char*)d_ws;
    f16* WqT = (f16*)p; p += NW * 2;
    f16* WkT = (f16*)p; p += NW * 2;
    f16* WvT = (f16*)p; p += NW * 2;
    f16* WoT = (f16*)p; p += NW * 2;
    f16* Qh  = (f16*)p; p += NQ_ELEMS * 2;
    f16* Kh  = (f16*)p; p += NKV_ELEMS * 2;
    f16* Vh  = (f16*)p; p += NKV_ELEMS * 2;
    float* attnw = (float*)p; p += (size_t)B_ * LKV_ * NH * SPAN * 4;
    f16* ctxh = (f16*)p; p += NQ_ELEMS * 2;

    // 1) weight transposes only (q/k/v convert folded into gemm_qkv)
    transpose_all<<<dim3(1024), 256, 0, stream>>>(Wq, Wk, Wv, Wo,
                                                  WqT, WkT, WvT, WoT);

    // 2) Q/K/V projections, pipelined 256x256, 1 block/CU
    gemm_qkv<<<dim3(256), 512, 0, stream>>>(q, k, v, WqT, WkT, WvT, Qh, Kh, Vh);

    // 3) per-column masked scores + query-axis softmax
    attn_scores<<<dim3(LKV_ / 4, B_), 256, 0, stream>>>(Qh, Kh, attnw);

    // 4) per-query gather of weighted V
    ctx_gather<<<dim3(LQ_ / 16, B_), 256, 0, stream>>>(attnw, Vh, ctxh);

    // 5) output projection, pipelined 256x128
    gemm_out<<<dim3(256), 512, 0, stream>>>(ctxh, WoT, out);
}